// Round 16
// baseline (363.749 us; speedup 1.0000x reference)
//
#include <hip/hip_runtime.h>
#include <hip/hip_bf16.h>
#include <math.h>

// Problem constants
#define BB 32
#define LL 300
#define TT 12
#define HH 256
#define EE 128
#define VV 50000
#define OOV 30
#define NPR 6
#define UNK 1
#define H2 512   // 2H
#define H3 768   // 3H
#define H4 1024  // 4H
#define BT (BB*TT)       // 384
#define NVB 391          // ceil(50000/128)
#define KSTEPS 24        // 768/32
#define NT32P (196*8)

// ---------------- ws layout (float offsets) ----------------
#define OFF_X        0                          // BT*EE
#define OFF_HID      (OFF_X + BT*EE)            // BT*HH
#define OFF_ENCP     (OFF_HID + BT*HH)          // BB*LL*H2
#define OFF_DECP     (OFF_ENCP + BB*LL*H2)      // BT*H2
#define OFF_ATTN     (OFF_DECP + BT*H2)         // BT*LL
#define OFF_S        (OFF_ATTN + BT*LL)         // BT*H3
#define OFF_PSW      (OFF_S + BT*H3)            // BT*3
#define OFF_COPY     (OFF_PSW + BT*3)           // BT
#define OFF_TLOGIT   (OFF_COPY + BT)            // BT
#define OFF_PMAX     (OFF_TLOGIT + BT)          // BT*NVB (legacy)
#define OFF_PSUM     (OFF_PMAX + BT*NVB)        // BT*NVB
#define OFF_NLL      (OFF_PSUM + BT*NVB)        // BT
#define OFF_APACK    (OFF_NLL + BT)             // BT*H3 shorts
#define OFF_XW       (OFF_APACK + BT*H3/2)      // BT*H4 floats
#define OFF_WHH      (OFF_XW + BT*H4)           // 131072 floats
#define OFF_HFRAG    (OFF_WHH + 131072)         // 8192 floats
#define OFF_BAR      (OFF_HFRAG + 8192)         // 64 floats
#define OFF_BPACK    (OFF_BAR + 64)
#define BPACK_SHORTS ((size_t)NT32P*24*2*64*8)
#define WS_NEEDED_BYTES ((size_t)(OFF_BPACK)*4 + BPACK_SHORTS*2)
// aliases inside BPACK region (dead before any reuse):
#define OFF_APENC (OFF_BPACK)                   // 9600*512 shorts
#define OFF_APHID (OFF_APENC + 2457600)         // 384*256 shorts
#define OFF_APX   (OFF_APHID + 49152)           // 384*128 shorts
#define OFF_BWIH  (OFF_APX + 24576)             // 128*1024 shorts
#define OFF_BWHW  (OFF_BWIH + 65536)            // 512*512 shorts
#define OFF_BWSW  (OFF_BWHW + 131072)           // 256*512 shorts

typedef __attribute__((ext_vector_type(8))) short short8;
typedef __attribute__((ext_vector_type(16))) float floatx16;

__device__ __forceinline__ short f2bf(float f) {
    __hip_bfloat16 h = __float2bfloat16(f);
    return *reinterpret_cast<short*>(&h);
}
__device__ __forceinline__ float bf2f(short s) {
    unsigned int u = ((unsigned int)(unsigned short)s) << 16;
    return __uint_as_float(u);
}
__device__ __forceinline__ float sigm(float x) { return 1.f/(1.f + expf(-x)); }

// async global->LDS, 16B per lane; lds dest = wave-uniform base + lane*16
__device__ __forceinline__ void gload_lds16(const float* g, float* l) {
    __builtin_amdgcn_global_load_lds(
        (const __attribute__((address_space(1))) void*)g,
        (__attribute__((address_space(3))) void*)l, 16, 0, 0);
}

// ---------------- K0: embedding lookup ----------------
__global__ __launch_bounds__(256) void k_embed(
    const float* __restrict__ embed, const int* __restrict__ dec_input,
    float* __restrict__ x_out)
{
    int i = blockIdx.x*256 + threadIdx.x;
    int bt = i >> 5;
    int e4 = i & 31;
    int tok = dec_input[bt];
    reinterpret_cast<float4*>(x_out)[(size_t)bt*32 + e4] =
        reinterpret_cast<const float4*>(embed)[(size_t)tok*32 + e4];
}

// ---------------- generic A-pack: A [M,K] fp32 -> 32x32x16 A-frag bf16 ------
__global__ __launch_bounds__(256) void k_apack(
    const float* __restrict__ A, short* __restrict__ Ap, int MT, int K_)
{
    int s = blockIdx.x*256 + threadIdx.x;
    int l = s & 63;
    int ks = (s >> 6) & 1;
    int rest = s >> 7;
    int mt = rest % MT;
    int kstep = rest / MT;
    int row = mt*32 + (l & 31);
    int kb = kstep*32 + ks*16 + ((l >> 5) << 3);
    const float4* src = reinterpret_cast<const float4*>(&A[(size_t)row*K_ + kb]);
    float4 a = src[0], b = src[1];
    short8 v;
    v[0]=f2bf(a.x); v[1]=f2bf(a.y); v[2]=f2bf(a.z); v[3]=f2bf(a.w);
    v[4]=f2bf(b.x); v[5]=f2bf(b.y); v[6]=f2bf(b.z); v[7]=f2bf(b.w);
    *reinterpret_cast<short8*>(Ap + (size_t)s*8) = v;
}

// ---------------- generic W-pack: W [K,N] fp32 -> 32x32x16 B-frag bf16 ------
__global__ __launch_bounds__(256) void k_wpack(
    const float* __restrict__ W, short* __restrict__ Bp, int KS, int N_)
{
    int s = blockIdx.x*256 + threadIdx.x;
    int l = s & 63;
    int ks = (s >> 6) & 1;
    int rest = s >> 7;
    int kstep = rest % KS;
    int ct = rest / KS;
    int col = ct*32 + (l & 31);
    int kb = kstep*32 + ks*16 + ((l >> 5) << 3);
    short8 v;
    #pragma unroll
    for (int j = 0; j < 8; ++j) v[j] = f2bf(W[(size_t)(kb + j)*N_ + col]);
    *reinterpret_cast<short8*>(Bp + (size_t)s*8) = v;
}

// ---------------- generic packed MFMA GEMM + bias: C[M,N] fp32 --------------
__global__ __launch_bounds__(512, 1) void k_gemm_mfma(
    const short* __restrict__ Apack, const short* __restrict__ Bpack,
    const float* __restrict__ bias, float* __restrict__ C,
    int N_, int MT, int KS)
{
    int bm = blockIdx.x, nb = blockIdx.y;
    int t = threadIdx.x;
    int wid = t >> 6, lane = t & 63;
    int wave_m = wid >> 2, wave_n = wid & 3;
    int mt0 = bm*6 + wave_m*3;
    int ct = nb*4 + wave_n;

    const short8* ap = reinterpret_cast<const short8*>(Apack);
    const short8* bp = reinterpret_cast<const short8*>(Bpack);

    floatx16 acc[3];
    #pragma unroll
    for (int mi = 0; mi < 3; ++mi)
        #pragma unroll
        for (int r = 0; r < 16; ++r) acc[mi][r] = 0.f;

    short8 Ba0, Ba1, Bb0, Bb1;
    short8 Fa[6], Fb[6];

#define LOADB(B0, B1, kst) do { \
    B0 = bp[(size_t)(((ct*KS + (kst))*2 + 0)*64 + lane)]; \
    B1 = bp[(size_t)(((ct*KS + (kst))*2 + 1)*64 + lane)]; \
} while (0)
#define LOADA(F, kst) do { \
    _Pragma("unroll") \
    for (int mi = 0; mi < 3; ++mi) { \
        F[mi]   = ap[(size_t)((((kst)*MT + (mt0 + mi))*2 + 0)*64 + lane)]; \
        F[3+mi] = ap[(size_t)((((kst)*MT + (mt0 + mi))*2 + 1)*64 + lane)]; \
    } \
} while (0)
#define STEP(B0, B1, F) do { \
    _Pragma("unroll") \
    for (int mi = 0; mi < 3; ++mi) \
        acc[mi] = __builtin_amdgcn_mfma_f32_32x32x16_bf16(F[mi], B0, acc[mi], 0, 0, 0); \
    _Pragma("unroll") \
    for (int mi = 0; mi < 3; ++mi) \
        acc[mi] = __builtin_amdgcn_mfma_f32_32x32x16_bf16(F[3+mi], B1, acc[mi], 0, 0, 0); \
} while (0)

    LOADB(Ba0, Ba1, 0); LOADA(Fa, 0);
    LOADB(Bb0, Bb1, 1); LOADA(Fb, 1);
    for (int k = 0; k < KS; k += 2) {
        STEP(Ba0, Ba1, Fa);
        if (k + 2 < KS) { LOADB(Ba0, Ba1, k+2); LOADA(Fa, k+2); }
        STEP(Bb0, Bb1, Fb);
        if (k + 3 < KS) { LOADB(Bb0, Bb1, k+3); LOADA(Fb, k+3); }
    }
#undef LOADB
#undef LOADA
#undef STEP

    int col = ct*32 + (lane & 31);
    float bias_v = bias[col];
    int rsub = 4*(lane >> 5);
    #pragma unroll
    for (int mi = 0; mi < 3; ++mi) {
        int rowg0 = bm*192 + wave_m*96 + mi*32 + rsub;
        #pragma unroll
        for (int r = 0; r < 16; ++r) {
            int rowg = rowg0 + (r & 3) + 8*(r >> 2);
            C[(size_t)rowg*N_ + col] = acc[mi][r] + bias_v;
        }
    }
}

// ---------------- fallback fp32 GEMM + bias ----------------
__global__ __launch_bounds__(256) void k_gemm_bias(
    const float* __restrict__ A, const float* __restrict__ Wm,
    const float* __restrict__ bias, float* __restrict__ C, int N_, int K_)
{
    __shared__ float As[64][17];
    __shared__ __align__(16) float Bs[16][128];
    int bm = blockIdx.x*64, bn = blockIdx.y*128;
    int tid = threadIdx.x, tr = tid >> 4, tc = tid & 15;
    float acc[4][8] = {};
    for (int k0 = 0; k0 < K_; k0 += 16) {
        for (int i = tid; i < 64*16; i += 256) { int r = i >> 4, c = i & 15; As[r][c] = A[(size_t)(bm+r)*K_ + k0 + c]; }
        for (int i = tid; i < 16*128; i += 256) { int r = i >> 7, c = i & 127; Bs[r][c] = Wm[(size_t)(k0+r)*N_ + bn + c]; }
        __syncthreads();
        #pragma unroll
        for (int kk = 0; kk < 16; ++kk) {
            float a0 = As[tr*4+0][kk], a1 = As[tr*4+1][kk], a2 = As[tr*4+2][kk], a3 = As[tr*4+3][kk];
            const float4* bpx = reinterpret_cast<const float4*>(&Bs[kk][tc*8]);
            float4 q0 = bpx[0], q1 = bpx[1];
            float bb[8] = {q0.x,q0.y,q0.z,q0.w,q1.x,q1.y,q1.z,q1.w};
            #pragma unroll
            for (int j = 0; j < 8; ++j) {
                acc[0][j] += a0*bb[j]; acc[1][j] += a1*bb[j];
                acc[2][j] += a2*bb[j]; acc[3][j] += a3*bb[j];
            }
        }
        __syncthreads();
    }
    for (int i = 0; i < 4; ++i) {
        int r = bm + tr*4 + i;
        for (int j = 0; j < 8; ++j) {
            int c = bn + tc*8 + j;
            C[(size_t)r*N_ + c] = acc[i][j] + bias[c];
        }
    }
}

// ---------------- W_hh -> per-block-sliced 32x32x16 B-frag order ------------
__global__ __launch_bounds__(256) void k_whh_pack(
    const float* __restrict__ Whh, short* __restrict__ wp)
{
    int s = blockIdx.x*256 + threadIdx.x;
    int l = s & 63;
    int kstep = (s >> 6) & 15;
    int ct_l = (s >> 10) & 7;
    int q = s >> 13;
    int col = (ct_l >> 1)*256 + q*64 + (ct_l & 1)*32 + (l & 31);
    int kb = kstep*16 + ((l >> 5) << 3);
    short8 v;
    #pragma unroll
    for (int j = 0; j < 8; ++j) v[j] = f2bf(Whh[(size_t)(kb + j)*H4 + col]);
    *reinterpret_cast<short8*>(wp + (size_t)s*8) = v;
}

// ---------------- init h0 -> hfrag buf0 + zero barriers ----------------
__global__ __launch_bounds__(256) void k_init(
    const float* __restrict__ h0, short* __restrict__ hbuf0,
    unsigned int* __restrict__ bar)
{
    int gid = blockIdx.x*256 + threadIdx.x;
    int r = gid >> 8;
    int hidx = gid & 255;
    int kstep = hidx >> 4;
    int kk = hidx & 15;
    int l = ((kk >> 3) << 5) + r;
    hbuf0[(size_t)(kstep*64 + l)*8 + (kk & 7)] = f2bf(h0[r*HH + hidx]);
    if (blockIdx.x == 0 && threadIdx.x < 64) bar[threadIdx.x] = 0u;
}

// ---------------- column-split MFMA LSTM, 4 blocks, W-slice in LDS ----------
__global__ __launch_bounds__(512) void k_lstm5(
    const float* __restrict__ xw, const short* __restrict__ whhp,
    const float* __restrict__ c0, short* __restrict__ hbuf,
    unsigned int* __restrict__ bar, float* __restrict__ hid_out)
{
    __shared__ short wlds[8*16*64*8];   // 128 KB
    __shared__ short g_lds[32][256];    // 16 KB
    __shared__ float c_lds[32][64];     // 8 KB
    int tid = threadIdx.x, wid = tid >> 6, lane = tid & 63;
    int q = blockIdx.x;

    {
        const short8* wp8 = reinterpret_cast<const short8*>(whhp);
        for (int i = tid; i < 8192; i += 512)
            *reinterpret_cast<short8*>(&wlds[i*8]) = wp8[(size_t)q*8192 + i];
    }
    for (int i = tid; i < 32*64; i += 512) {
        int b = i >> 6, jj = i & 63;
        c_lds[b][jj] = c0[b*HH + q*64 + jj];
    }
    __syncthreads();

    for (int t = 0; t < TT; ++t) {
        const short* hcur = hbuf + (size_t)(t & 1)*8192;
        short* hnxt = hbuf + (size_t)((t + 1) & 1)*8192;

        floatx16 acc;
        #pragma unroll
        for (int r = 0; r < 16; ++r) acc[r] = 0.f;
        #pragma unroll
        for (int kstep = 0; kstep < 16; ++kstep) {
            short8 af = *reinterpret_cast<const short8*>(&hcur[(size_t)(kstep*64 + lane)*8]);
            short8 bf = *reinterpret_cast<const short8*>(&wlds[((wid*16 + kstep)*64 + lane)*8]);
            acc = __builtin_amdgcn_mfma_f32_32x32x16_bf16(af, bf, acc, 0, 0, 0);
        }
        int gcol = (wid >> 1)*256 + q*64 + (wid & 1)*32 + (lane & 31);
        int lcol = wid*32 + (lane & 31);
        #pragma unroll
        for (int r = 0; r < 16; ++r) {
            int row = (r & 3) + 8*(r >> 2) + 4*(lane >> 5);
            g_lds[row][lcol] = f2bf(acc[r] + xw[(size_t)(row*TT + t)*H4 + gcol]);
        }
        __syncthreads();
        for (int i = tid; i < 2048; i += 512) {
            int b = i >> 6, jj = i & 63;
            float gi = bf2f(g_lds[b][((0*2 + (jj>>5))<<5) + (jj & 31)]);
            float gf = bf2f(g_lds[b][((1*2 + (jj>>5))<<5) + (jj & 31)]);
            float gg = bf2f(g_lds[b][((2*2 + (jj>>5))<<5) + (jj & 31)]);
            float go = bf2f(g_lds[b][((3*2 + (jj>>5))<<5) + (jj & 31)]);
            float c = sigm(gf)*c_lds[b][jj] + sigm(gi)*tanhf(gg);
            float h = sigm(go)*tanhf(c);
            c_lds[b][jj] = c;
            int hidx = q*64 + jj;
            hid_out[(size_t)(b*TT + t)*HH + hidx] = h;
            int kk = hidx & 15;
            int l2 = ((kk >> 3) << 5) + b;
            hnxt[(size_t)((hidx >> 4)*64 + l2)*8 + (kk & 7)] = f2bf(h);
        }
        __threadfence();
        __syncthreads();
        if (tid == 0) {
            atomicAdd(&bar[t], 1u);
            while (atomicAdd(&bar[t], 0u) < 4u) __builtin_amdgcn_s_sleep(2);
        }
        __syncthreads();
        __threadfence();
    }
}

// ---------------- K4: e scores ----------------
__global__ __launch_bounds__(256) void k_e(
    const float* __restrict__ enc_proj, const float* __restrict__ dec_proj,
    const float* __restrict__ v_w, const float* __restrict__ v_b,
    const unsigned char* __restrict__ enc_mask, float* __restrict__ e_out)
{
    int b = blockIdx.x, lbase = blockIdx.y*4;
    __shared__ float decp[TT*H2];
    int tid = threadIdx.x;
    for (int i = tid; i < TT*H2; i += 256) decp[i] = dec_proj[(size_t)b*TT*H2 + i];
    __syncthreads();
    int wave = tid >> 6, lane = tid & 63;
    int l = lbase + wave;
    const float* er = &enc_proj[(size_t)(b*LL + l)*H2];
    float ep[8], vw[8];
    #pragma unroll
    for (int k = 0; k < 8; ++k) { int e = lane + 64*k; ep[k] = er[e]; vw[k] = v_w[e]; }
    float vb = v_b[0];
    bool masked = enc_mask[b*LL + l] != 0;
    for (int t = 0; t < TT; ++t) {
        float acc = 0.f;
        #pragma unroll
        for (int k = 0; k < 8; ++k) {
            int e = lane + 64*k;
            acc += vw[k] * tanhf(ep[k] + decp[t*H2 + e]);
        }
        #pragma unroll
        for (int off = 32; off; off >>= 1) acc += __shfl_xor(acc, off);
        if (lane == 0)
            e_out[(size_t)(b*TT + t)*LL + l] = masked ? -INFINITY : (acc + vb);
    }
}

// ---------------- K5: softmax over L + context + s ----------------
__global__ __launch_bounds__(256) void k_softmax_ctx(
    float* __restrict__ attn, const float* __restrict__ enc_states,
    const float* __restrict__ hidden, float* __restrict__ s_out)
{
    int bt = blockIdx.x, b = bt / TT, tid = threadIdx.x;
    __shared__ float a[LL];
    __shared__ float red[256];
    float m = -INFINITY;
    for (int l = tid; l < LL; l += 256) m = fmaxf(m, attn[(size_t)bt*LL + l]);
    red[tid] = m; __syncthreads();
    for (int s = 128; s; s >>= 1) { if (tid < s) red[tid] = fmaxf(red[tid], red[tid+s]); __syncthreads(); }
    m = red[0]; __syncthreads();
    float sum = 0.f;
    for (int l = tid; l < LL; l += 256) { float w = expf(attn[(size_t)bt*LL + l] - m); a[l] = w; sum += w; }
    red[tid] = sum; __syncthreads();
    for (int s = 128; s; s >>= 1) { if (tid < s) red[tid] += red[tid+s]; __syncthreads(); }
    float inv = 1.0f / red[0];
    __syncthreads();
    for (int l = tid; l < LL; l += 256) { float w = a[l]*inv; a[l] = w; attn[(size_t)bt*LL + l] = w; }
    __syncthreads();
    for (int c = tid; c < H2; c += 256) {
        float acc = 0.f;
        const float* es = &enc_states[(size_t)b*LL*H2 + c];
        for (int l = 0; l < LL; ++l) acc += a[l] * es[(size_t)l*H2];
        s_out[(size_t)bt*H3 + HH + c] = acc;
    }
    for (int c = tid; c < HH; c += 256) s_out[(size_t)bt*H3 + c] = hidden[(size_t)bt*HH + c];
}

// ---------------- K6: switch softmax + copy score ----------------
__global__ __launch_bounds__(64) void k_switch_copy(
    const float* __restrict__ s, const float* __restrict__ x,
    const float* __restrict__ enc_h0,
    const float* __restrict__ wh_w, const float* __restrict__ wh_b,
    const float* __restrict__ ws_w, const float* __restrict__ ws_b,
    const float* __restrict__ wx_w, const float* __restrict__ wx_b,
    const float* __restrict__ wc_w, const float* __restrict__ wc_b,
    const int* __restrict__ article_inds, const int* __restrict__ targets,
    const float* __restrict__ attn, float* __restrict__ psw, float* __restrict__ copysc)
{
    int bt = blockIdx.x, b = bt / TT, lane = threadIdx.x;
    float s0 = 0.f, s1 = 0.f, s2 = 0.f;
    const float* ctx = &s[(size_t)bt*H3 + HH];
    const float* hid = &s[(size_t)bt*H3];
    for (int k = lane; k < H2; k += 64) { float v = ctx[k]; s0 += v*wh_w[k*3]; s1 += v*wh_w[k*3+1]; s2 += v*wh_w[k*3+2]; }
    for (int k = lane; k < HH; k += 64) { float v = hid[k]; s0 += v*ws_w[k*3]; s1 += v*ws_w[k*3+1]; s2 += v*ws_w[k*3+2]; }
    for (int k = lane; k < EE; k += 64) { float v = x[(size_t)bt*EE + k]; s0 += v*wx_w[k*3]; s1 += v*wx_w[k*3+1]; s2 += v*wx_w[k*3+2]; }
    for (int k = lane; k < HH; k += 64) { float v = enc_h0[b*HH + k]; s0 += v*wc_w[k*3]; s1 += v*wc_w[k*3+1]; s2 += v*wc_w[k*3+2]; }
    #pragma unroll
    for (int off = 32; off; off >>= 1) {
        s0 += __shfl_xor(s0, off); s1 += __shfl_xor(s1, off); s2 += __shfl_xor(s2, off);
    }
    if (lane == 0) {
        s0 += wh_b[0] + ws_b[0] + wx_b[0] + wc_b[0];
        s1 += wh_b[1] + ws_b[1] + wx_b[1] + wc_b[1];
        s2 += wh_b[2] + ws_b[2] + wx_b[2] + wc_b[2];
        float mm = fmaxf(s0, fmaxf(s1, s2));
        float e0 = expf(s0-mm), e1 = expf(s1-mm), e2 = expf(s2-mm);
        float inv = 1.f/(e0+e1+e2);
        psw[bt*3+0] = e0*inv; psw[bt*3+1] = e1*inv; psw[bt*3+2] = e2*inv;
    }
    int tgt = targets[bt];
    float cs = 0.f;
    for (int l = lane; l < LL; l += 64)
        if (article_inds[b*LL + l] == tgt) cs += attn[(size_t)bt*LL + l];
    #pragma unroll
    for (int off = 32; off; off >>= 1) cs += __shfl_xor(cs, off);
    if (lane == 0) copysc[bt] = cs;
}

// ---------------- K7f: fused one-pass big GEMM --------------------------
// grid(391), 512 thr (8 waves = 2m x 4n, 6 acc tiles/wave = all 384 rows).
// Per K-step: stage [32k x 128col] fp32 Vout_w tile (16 KB) to LDS via
// global_load_lds (coalesced, double-buffered, 1 barrier/step), convert to
// bf16 in regs, 12 MFMA/wave. B read from HBM exactly ONCE (153.6 MB).
__global__ __launch_bounds__(512, 1) void k_big_fused(
    const short* __restrict__ Apack, const float* __restrict__ Wm,
    const float* __restrict__ bias, const int* __restrict__ targets,
    float* __restrict__ psum, float* __restrict__ tlogit)
{
    __shared__ float btile[2][32*128];   // 2 x 16 KB
    __shared__ float pv_l[384][4];       // 6 KB
    int nvb = blockIdx.x;
    int bn = nvb * 128;
    int t = threadIdx.x;
    int wid = t >> 6, lane = t & 63;
    int wave_m = wid >> 2, wave_n = wid & 3;

    // staging: granule col (4 floats); clamp OOB to row start (garbage cols
    // discarded in epilogue via colOK)
    int gcol = bn + ((lane & 31) << 2);
    bool gOK = gcol <= (VV - 4);
    int goff = gOK ? gcol : 0;

    const short8* ap = reinterpret_cast<const short8*>(Apack);

    floatx16 acc[6];
    #pragma unroll
    for (int mi = 0; mi < 6; ++mi)
        #pragma unroll
        for (int r = 0; r < 16; ++r) acc[mi][r] = 0.f;

#define STAGE(buf, kst) do { \
    _Pragma("unroll") \
    for (int rr = 0; rr < 2; ++rr) { \
        int row = rr*16 + wid*2 + (lane >> 5); \
        const float* g = Wm + (size_t)((kst)*32 + row)*VV + goff; \
        float* l = &btile[buf][(rr*16 + wid*2)*128]; \
        gload_lds16(g, l); \
    } \
} while (0)

    STAGE(0, 0);
    __syncthreads();

    int cb = wave_n*32 + (lane & 31);
    int k0r = (lane >> 5) << 3;
    for (int k = 0; k < KSTEPS; ++k) {
        int cur = k & 1;
        if (k + 1 < KSTEPS) STAGE(cur ^ 1, k + 1);
        short8 bf0, bf1;
        #pragma unroll
        for (int j = 0; j < 8; ++j) bf0[j] = f2bf(btile[cur][(k0r + j)*128 + cb]);
        #pragma unroll
        for (int j = 0; j < 8; ++j) bf1[j] = f2bf(btile[cur][(16 + k0r + j)*128 + cb]);
        #pragma unroll
        for (int mi = 0; mi < 6; ++mi) {
            short8 af0 = ap[(size_t)((k*12 + (wave_m*6 + mi))*2 + 0)*64 + lane];
            acc[mi] = __builtin_amdgcn_mfma_f32_32x32x16_bf16(af0, bf0, acc[mi], 0, 0, 0);
            short8 af1 = ap[(size_t)((k*12 + (wave_m*6 + mi))*2 + 1)*64 + lane];
            acc[mi] = __builtin_amdgcn_mfma_f32_32x32x16_bf16(af1, bf1, acc[mi], 0, 0, 0);
        }
        __syncthreads();   // drains staging (auto vmcnt(0)) + buffer handoff
    }
#undef STAGE

    // epilogue: per-row sum of exp(logit) over this block's 128 cols (M=0)
    int colW = bn + wave_n*32 + (lane & 31);
    bool colOK = colW < VV;
    float bias_v = colOK ? bias[colW] : 0.f;
    int rsub = 4*(lane >> 5);
    #pragma unroll
    for (int mi = 0; mi < 6; ++mi) {
        #pragma unroll
        for (int r = 0; r < 16; ++r) {
            int rowg = wave_m*192 + mi*32 + rsub + (r & 3) + 8*(r >> 2);
            float logit = acc[mi][r] + bias_v;
            if (colOK && colW == targets[rowg]) tlogit[rowg] = logit;
            float e = colOK ? expf(logit) : 0.f;
            #pragma unroll
            for (int msk = 16; msk; msk >>= 1) e += __shfl_xor(e, msk);
            if ((lane & 31) == 0) pv_l[rowg][wave_n] = e;
        }
    }
    __syncthreads();
    if (t < 384) {
        float ss = pv_l[t][0] + pv_l[t][1] + pv_l[t][2] + pv_l[t][3];
        psum[(size_t)t*NVB + nvb] = ss;
    }
}

// ---------------- K7: legacy direct-read k_big (ws fallback, bf16) ----------
__global__ __launch_bounds__(512) void k_big(
    const short* __restrict__ Apack, const float* __restrict__ Wm,
    const float* __restrict__ bias, const int* __restrict__ targets,
    float* __restrict__ psum, float* __restrict__ tlogit)
{
    __shared__ float pv_l[192][4];
    int bm = blockIdx.x, nvb = blockIdx.y;
    int bn = nvb * 128;
    int t = threadIdx.x;
    int wid = t >> 6, lane = t & 63;
    int wave_m = wid >> 2, wave_n = wid & 3;
    int colB = bn + wave_n*32 + (lane & 31);
    int kOff = (lane >> 5) << 3;
    bool colOK = colB < VV;
    int mt0 = bm*6 + wave_m*3;
    const short8* ap = reinterpret_cast<const short8*>(Apack);
    floatx16 acc[3];
    #pragma unroll
    for (int mi = 0; mi < 3; ++mi)
        #pragma unroll
        for (int r = 0; r < 16; ++r) acc[mi][r] = 0.f;
    float Bq0a[8], Bq1a[8], Bq0b[8], Bq1b[8];
    short8 Fa[6], Fb[6];
#define LOADB(Q0, Q1, kst) do { \
    int kb_ = (kst)*32 + kOff; \
    _Pragma("unroll") \
    for (int j = 0; j < 8; ++j) Q0[j] = colOK ? Wm[(size_t)(kb_ + j)*VV + colB] : 0.f; \
    _Pragma("unroll") \
    for (int j = 0; j < 8; ++j) Q1[j] = colOK ? Wm[(size_t)(kb_ + 16 + j)*VV + colB] : 0.f; \
} while (0)
#define LOADA(F, kst) do { \
    _Pragma("unroll") \
    for (int mi = 0; mi < 3; ++mi) { \
        F[mi]   = ap[(size_t)(((kst)*12 + (mt0 + mi))*2 + 0)*64 + lane]; \
        F[3+mi] = ap[(size_t)(((kst)*12 + (mt0 + mi))*2 + 1)*64 + lane]; \
    } \
} while (0)
#define STEP(Q0, Q1, F) do { \
    short8 b0_, b1_; \
    _Pragma("unroll") \
    for (int j = 0; j < 8; ++j) { b0_[j] = f2bf(Q0[j]); b1_[j] = f2bf(Q1[j]); } \
    _Pragma("unroll") \
    for (int mi = 0; mi < 3; ++mi) \
        acc[mi] = __builtin_amdgcn_mfma_f32_32x32x16_bf16(F[mi], b0_, acc[mi], 0, 0, 0); \
    _Pragma("unroll") \
    for (int mi = 0; mi < 3; ++mi) \
        acc[mi] = __builtin_amdgcn_mfma_f32_32x32x16_bf16(F[3+mi], b1_, acc[mi], 0, 0, 0); \
} while (0)
    LOADB(Bq0a, Bq1a, 0); LOADA(Fa, 0);
    LOADB(Bq0b, Bq1b, 1); LOADA(Fb, 1);
    for (int k = 0; k < KSTEPS; k += 2) {
        STEP(Bq0a, Bq1a, Fa);
        if (k + 2 < KSTEPS) { LOADB(Bq0a, Bq1a, k+2); LOADA(Fa, k+2); }
        STEP(Bq0b, Bq1b, Fb);
        if (k + 3 < KSTEPS) { LOADB(Bq0b, Bq1b, k+3); LOADA(Fb, k+3); }
    }
#undef LOADB
#undef LOADA
#undef STEP
    float bias_v = colOK ? bias[colB] : 0.f;
    int rsub = 4*(lane >> 5);
    #pragma unroll
    for (int mi = 0; mi < 3; ++mi) {
        #pragma unroll
        for (int r = 0; r < 16; ++r) {
            int row_l = wave_m*96 + mi*32 + rsub + (r & 3) + 8*(r >> 2);
            int rowg = bm*192 + row_l;
            float logit = acc[mi][r] + bias_v;
            if (colOK && colB == targets[rowg]) tlogit[rowg] = logit;
            float e = colOK ? expf(logit) : 0.f;
            #pragma unroll
            for (int msk = 16; msk; msk >>= 1) e += __shfl_xor(e, msk);
            if ((lane & 31) == 0) pv_l[row_l][wave_n] = e;
        }
    }
    __syncthreads();
    if (t < 192) {
        float ss = pv_l[t][0] + pv_l[t][1] + pv_l[t][2] + pv_l[t][3];
        int rowg = bm*192 + t;
        psum[(size_t)rowg*NVB + nvb] = ss;
    }
}

// ---------------- K8: sum partials + per-token nll ----------------
__global__ __launch_bounds__(64) void k_lsum(
    const float* __restrict__ psum,
    const float* __restrict__ tlogit, const int* __restrict__ targets,
    const float* __restrict__ psw, const float* __restrict__ copysc,
    const float* __restrict__ dec_mask, float* __restrict__ nll)
{
    int pair = blockIdx.x, lane = threadIdx.x;
    float s = 0.f;
    for (int j = lane; j < NVB; j += 64) s += psum[(size_t)pair*NVB + j];
    #pragma unroll
    for (int off = 32; off; off >>= 1) s += __shfl_xor(s, off);
    if (lane == 0) {
        int tgt = targets[pair];
        float outv;
        if (tgt == UNK) outv = 1.0f;
        else {
            float base = 0.f;
            if (tgt < VV) {
                float pvv = expf(tlogit[pair]) / s;
                float pg = (tgt < VV - NPR) ? psw[pair*3] : psw[pair*3+1];
                base = pg * pvv;
            }
            outv = base + psw[pair*3+2] * copysc[pair];
        }
        outv = fmaxf(outv, 1e-38f);
        nll[pair] = -logf(outv) * dec_mask[pair];
    }
}

// ---------------- K9: final per-batch loss ----------------
__global__ __launch_bounds__(64) void k_final(
    const float* __restrict__ nll, const float* __restrict__ dec_lens, float* __restrict__ out)
{
    int b = threadIdx.x;
    if (b < BB) {
        float a = 0.f;
        for (int t = 0; t < TT; ++t) a += nll[b*TT + t];
        out[b] = a / dec_lens[b];
    }
}

extern "C" void kernel_launch(void* const* d_in, const int* in_sizes, int n_in,
                              void* d_out, int out_size, void* d_ws, size_t ws_size,
                              hipStream_t stream)
{
    const float* enc_states = (const float*)d_in[0];
    const float* enc_h0     = (const float*)d_in[1];
    const float* enc_c0     = (const float*)d_in[2];
    const unsigned char* enc_mask = (const unsigned char*)d_in[3];
    const int* article_inds = (const int*)d_in[4];
    const int* dec_input    = (const int*)d_in[5];
    const int* targets      = (const int*)d_in[6];
    const float* dec_lens   = (const float*)d_in[7];
    const float* dec_mask   = (const float*)d_in[8];
    const float* embed      = (const float*)d_in[9];
    const float* W_ih       = (const float*)d_in[10];
    const float* W_hh       = (const float*)d_in[11];
    const float* b_lstm     = (const float*)d_in[12];
    const float* Wh_w = (const float*)d_in[13]; const float* Wh_b = (const float*)d_in[14];
    const float* Ws_w = (const float*)d_in[15]; const float* Ws_b = (const float*)d_in[16];
    const float* v_w  = (const float*)d_in[17]; const float* v_b  = (const float*)d_in[18];
    const float* wh_w = (const float*)d_in[19]; const float* wh_b = (const float*)d_in[20];
    const float* ws_w = (const float*)d_in[21]; const float* ws_b = (const float*)d_in[22];
    const float* wx_w = (const float*)d_in[23]; const float* wx_b = (const float*)d_in[24];
    const float* wc_w = (const float*)d_in[25]; const float* wc_b = (const float*)d_in[26];
    const float* Vout_w = (const float*)d_in[27]; const float* Vout_b = (const float*)d_in[28];

    float* ws = (float*)d_ws;
    float* x_buf   = ws + OFF_X;
    float* hid     = ws + OFF_HID;
    float* encp    = ws + OFF_ENCP;
    float* decp    = ws + OFF_DECP;
    float* attn    = ws + OFF_ATTN;
    float* s_buf   = ws + OFF_S;
    float* psw     = ws + OFF_PSW;
    float* copysc  = ws + OFF_COPY;
    float* tlogit  = ws + OFF_TLOGIT;
    float* psum    = ws + OFF_PSUM;
    float* nll     = ws + OFF_NLL;
    short* apack   = (short*)(ws + OFF_APACK);
    float* xw      = ws + OFF_XW;
    short* whhp    = (short*)(ws + OFF_WHH);
    short* hbuf    = (short*)(ws + OFF_HFRAG);
    unsigned int* bar = (unsigned int*)(ws + OFF_BAR);
    // aliases inside the BPACK region:
    short* apenc   = (short*)(ws + OFF_APENC);
    short* aphid   = (short*)(ws + OFF_APHID);
    short* apx     = (short*)(ws + OFF_APX);
    short* bwih    = (short*)(ws + OFF_BWIH);
    short* bwhw    = (short*)(ws + OFF_BWHW);
    short* bwsw    = (short*)(ws + OFF_BWSW);
    float* out     = (float*)d_out;

    bool use_pack = ws_size >= WS_NEEDED_BYTES;

    // 1a. embedding lookup
    k_embed<<<dim3(BT*EE/4/256), dim3(256), 0, stream>>>(embed, dec_input, x_buf);

    if (use_pack) {
        // 1b. xw = x @ W_ih + b_lstm  via MFMA
        k_apack<<<dim3(BT*EE/8/256), dim3(256), 0, stream>>>(x_buf, apx, 12, EE);
        k_wpack<<<dim3(EE*H4/8/256), dim3(256), 0, stream>>>(W_ih, bwih, EE/32, H4);
        k_gemm_mfma<<<dim3(BT/192, H4/128), dim3(512), 0, stream>>>(apx, bwih, b_lstm, xw, H4, BT/32, EE/32);
    } else {
        k_gemm_bias<<<dim3(BT/64, H4/128), dim3(256), 0, stream>>>(x_buf, W_ih, b_lstm, xw, H4, EE);
    }
    // 1c-1e. LSTM
    k_whh_pack<<<dim3(128), dim3(256), 0, stream>>>(W_hh, whhp);
    k_init<<<dim3(32), dim3(256), 0, stream>>>(enc_h0, hbuf, bar);
    k_lstm5<<<dim3(4), dim3(512), 0, stream>>>(xw, whhp, enc_c0, hbuf, bar, hid);

    if (use_pack) {
        // 2. enc_proj via MFMA
        k_apack<<<dim3(BB*LL*H2/8/256), dim3(256), 0, stream>>>(enc_states, apenc, BB*LL/32, H2);
        k_wpack<<<dim3(H2*H2/8/256), dim3(256), 0, stream>>>(Wh_w, bwhw, H2/32, H2);
        k_gemm_mfma<<<dim3(BB*LL/192, H2/128), dim3(512), 0, stream>>>(apenc, bwhw, Wh_b, encp, H2, BB*LL/32, H2/32);
        // 3. dec_proj via MFMA
        k_apack<<<dim3(BT*HH/8/256), dim3(256), 0, stream>>>(hid, aphid, 12, HH);
        k_wpack<<<dim3(HH*H2/8/256), dim3(256), 0, stream>>>(Ws_w, bwsw, HH/32, H2);
        k_gemm_mfma<<<dim3(BT/192, H2/128), dim3(512), 0, stream>>>(aphid, bwsw, Ws_b, decp, H2, BT/32, HH/32);
    } else {
        k_gemm_bias<<<dim3(BB*LL/64, H2/128), dim3(256), 0, stream>>>(enc_states, Wh_w, Wh_b, encp, H2, H2);
        k_gemm_bias<<<dim3(BT/64, H2/128), dim3(256), 0, stream>>>(hid, Ws_w, Ws_b, decp, H2, HH);
    }
    // 4. e scores
    k_e<<<dim3(BB, LL/4), dim3(256), 0, stream>>>(encp, decp, v_w, v_b, enc_mask, attn);
    // 5. softmax + context + s
    k_softmax_ctx<<<dim3(BT), dim3(256), 0, stream>>>(attn, enc_states, hid, s_buf);
    // 6. switch + copy score
    k_switch_copy<<<dim3(BT), dim3(64), 0, stream>>>(s_buf, x_buf, enc_h0,
        wh_w, wh_b, ws_w, ws_b, wx_w, wx_b, wc_w, wc_b,
        article_inds, targets, attn, psw, copysc);
    // 6.5 pack A (bf16)
    k_apack<<<dim3(BT*H3/8/256), dim3(256), 0, stream>>>(s_buf, apack, 12, H3);
    // 7. big GEMM: fused one-pass (global_load_lds staged) or legacy fallback
    if (use_pack) {
        k_big_fused<<<dim3(NVB), dim3(512), 0, stream>>>(apack, Vout_w, Vout_b, targets, psum, tlogit);
    } else {
        k_big<<<dim3(2, NVB), dim3(512), 0, stream>>>(apack, Vout_w, Vout_b, targets, psum, tlogit);
    }
    // 8. merge + nll
    k_lsum<<<dim3(BT), dim3(64), 0, stream>>>(psum, tlogit, targets, psw, copysc, dec_mask, nll);
    // 9. final loss
    k_final<<<dim3(1), dim3(64), 0, stream>>>(nll, dec_lens, out);
}